// Round 1
// 792.004 us; speedup vs baseline: 1.2066x; 1.2066x over previous
//
#include <hip/hip_runtime.h>
#include <cstdint>
#include <cstddef>

// Problem constants (hardcoded per reference setup_inputs)
#define B_    4
#define Q_    8192
#define E_    256
#define H_    8
#define L_    4
#define P_    4
#define HD_   32
#define VLEN_ 21760   // 128^2 + 64^2 + 32^2 + 16^2
#define K_    256

// ---------------- Kernel 1: value projection for ONE batch (all fp32) ----------------
// C[pix][n] = sum_k value_b[pix][k] * V_W[n][k]; C row-major (21760, 256) fp32.
// k-major LDS staging so fragment reads are ds_read_b128 (4 k at a time).
#define VSTEP(q) { \
  const float4 av  = *(const float4*)&Ak[kc*4+(q)][ty*4]; \
  const float4 wv4 = *(const float4*)&Wk[kc*4+(q)][tx*4]; \
  acc[0][0]+=av.x*wv4.x; acc[0][1]+=av.x*wv4.y; acc[0][2]+=av.x*wv4.z; acc[0][3]+=av.x*wv4.w; \
  acc[1][0]+=av.y*wv4.x; acc[1][1]+=av.y*wv4.y; acc[1][2]+=av.y*wv4.z; acc[1][3]+=av.y*wv4.w; \
  acc[2][0]+=av.z*wv4.x; acc[2][1]+=av.z*wv4.y; acc[2][2]+=av.z*wv4.z; acc[2][3]+=av.z*wv4.w; \
  acc[3][0]+=av.w*wv4.x; acc[3][1]+=av.w*wv4.y; acc[3][2]+=av.w*wv4.z; acc[3][3]+=av.w*wv4.w; }

__global__ __launch_bounds__(256)
void gemm_vproj(const float* __restrict__ A,      // value + b*VLEN*256
                const float* __restrict__ W,      // V_W (256,256)
                float* __restrict__ C)            // v_ws (21760,256) fp32
{
  // k-major chunk tiles: [kk][row], row-stride 68 floats (272 B, 16B-aligned, 2-way banks)
  __shared__ float Ak[16][68];
  __shared__ float Wk[16][68];

  const int t  = threadIdx.x;
  const int tx = t & 15, ty = t >> 4;
  const int bm = blockIdx.x, bn = blockIdx.y;
  const int lr  = t >> 2;          // 0..63: row within tile
  const int lc4 = (t & 3) * 4;     // k offset within chunk

  float acc[4][4] = {};

  for (int k0 = 0; k0 < K_; k0 += 16) {
    __syncthreads();
    {
      const float4 va = *(const float4*)(A + (size_t)(bm * 64 + lr) * K_ + k0 + lc4);
      Ak[lc4+0][lr] = va.x; Ak[lc4+1][lr] = va.y; Ak[lc4+2][lr] = va.z; Ak[lc4+3][lr] = va.w;
      const float4 vw = *(const float4*)(W + (size_t)(bn * 64 + lr) * K_ + k0 + lc4);
      Wk[lc4+0][lr] = vw.x; Wk[lc4+1][lr] = vw.y; Wk[lc4+2][lr] = vw.z; Wk[lc4+3][lr] = vw.w;
    }
    __syncthreads();
#pragma unroll
    for (int kc = 0; kc < 4; ++kc) {
      VSTEP(0) VSTEP(1) VSTEP(2) VSTEP(3)
    }
  }

#pragma unroll
  for (int i = 0; i < 4; ++i)
#pragma unroll
    for (int j = 0; j < 4; ++j) {
      const int gm = bm * 64 + ty * 4 + i;
      const int gn = bn * 64 + tx * 4 + j;
      C[(size_t)gm * 256 + gn] = acc[i][j];
    }
}

// ---------------- Kernel 2: fused offsets/attn GEMM + softmax + sampling (ONE batch) ----------------
// One block = 16 consecutive queries. Single K-loop: each thread owns 6 output
// columns (64c + lane), all 384 weight columns staged k-major in LDS per 16-k
// chunk. Q fragments are wave-uniform float4 broadcasts. The weight-chunk LDS
// buffer is dead after the K-loop and aliased with s_px/s_py/s_a.
#define FSTEP(q, COMP) { \
  const float* wr = &wck[kc*4+(q)][lane]; \
  const float w0=wr[0], w1=wr[64], w2=wr[128], w3=wr[192], w4=wr[256], w5=wr[320]; \
  acc[0][0]+=w0*qv0.COMP; acc[0][1]+=w0*qv1.COMP; acc[0][2]+=w0*qv2.COMP; acc[0][3]+=w0*qv3.COMP; \
  acc[1][0]+=w1*qv0.COMP; acc[1][1]+=w1*qv1.COMP; acc[1][2]+=w1*qv2.COMP; acc[1][3]+=w1*qv3.COMP; \
  acc[2][0]+=w2*qv0.COMP; acc[2][1]+=w2*qv1.COMP; acc[2][2]+=w2*qv2.COMP; acc[2][3]+=w2*qv3.COMP; \
  acc[3][0]+=w3*qv0.COMP; acc[3][1]+=w3*qv1.COMP; acc[3][2]+=w3*qv2.COMP; acc[3][3]+=w3*qv3.COMP; \
  acc[4][0]+=w4*qv0.COMP; acc[4][1]+=w4*qv1.COMP; acc[4][2]+=w4*qv2.COMP; acc[4][3]+=w4*qv3.COMP; \
  acc[5][0]+=w5*qv0.COMP; acc[5][1]+=w5*qv1.COMP; acc[5][2]+=w5*qv2.COMP; acc[5][3]+=w5*qv3.COMP; }

__global__ __launch_bounds__(256)
void fused_offattn_sample(const float* __restrict__ queries,     // + b*Q*256
                          const float* __restrict__ ref_points,  // + b*Q*8
                          const float* __restrict__ off_W,
                          const float* __restrict__ off_b,
                          const float* __restrict__ attn_W,
                          const float* __restrict__ attn_b,
                          const float* __restrict__ v_ws,        // (21760,256) fp32
                          float* __restrict__ outpre)            // (8192,256) fp32
{
  __shared__ float qs[16][260];            // query tile fp32 (pad 4, rows 16B-aligned)
  __shared__ float upool[16 * 384];        // union: wck[16][384] | {s_px,s_py,s_a}[16][128]
  __shared__ float refs[16][8];            // ref_points per query (l, xy)
  __shared__ int   s_idx[128 * 4];
  __shared__ float s_w[128 * 4];

  float (*wck)[384]  = (float (*)[384])upool;
  float (*s_px)[128] = (float (*)[128])upool;              // floats [0, 2048)
  float (*s_py)[128] = (float (*)[128])(upool + 16 * 128); // [2048, 4096)
  float (*s_a)[128]  = (float (*)[128])(upool + 32 * 128); // [4096, 6144)

  const int t     = threadIdx.x;
  const int lane  = t & 63;                // column within 64-col group
  const int wv    = t >> 6;                // wave id: q rows {wv, wv+4, wv+8, wv+12}
  const int qbase = blockIdx.x * 16;       // local query base within this batch

  // ---- load query tile + ref points
  {
    const int r  = t >> 4;
    const int c0 = (t & 15) * 16;
    const float4* src = (const float4*)(queries + (size_t)(qbase + r) * K_ + c0);
    *(float4*)&qs[r][c0 + 0]  = src[0];
    *(float4*)&qs[r][c0 + 4]  = src[1];
    *(float4*)&qs[r][c0 + 8]  = src[2];
    *(float4*)&qs[r][c0 + 12] = src[3];
  }
  if (t < 128) refs[t >> 3][t & 7] = ref_points[(size_t)(qbase + (t >> 3)) * 8 + (t & 7)];

  // ---- precompute weight-staging sources: 1536 float4 per chunk, 6 per thread
  const float* wsrc[6]; int wcol[6]; int wm4[6];
#pragma unroll
  for (int n = 0; n < 6; ++n) {
    const int e   = n * 256 + t;           // 0..1535
    const int col = e % 384;               // output column
    const int m   = e / 384;               // k-subgroup (0..3)
    wcol[n] = col; wm4[n] = m * 4;
    wsrc[n] = (col < 256 ? off_W + (size_t)col * K_
                         : attn_W + (size_t)(col - 256) * K_) + m * 4;
  }

  float acc[6][4] = {};   // [col-group c][q-row i]; col = c*64 + lane

  for (int k0 = 0; k0 < K_; k0 += 16) {
    __syncthreads();
#pragma unroll
    for (int n = 0; n < 6; ++n) {
      const float4 v = *(const float4*)(wsrc[n] + k0);
      wck[wm4[n] + 0][wcol[n]] = v.x;
      wck[wm4[n] + 1][wcol[n]] = v.y;
      wck[wm4[n] + 2][wcol[n]] = v.z;
      wck[wm4[n] + 3][wcol[n]] = v.w;
    }
    __syncthreads();
#pragma unroll
    for (int kc = 0; kc < 4; ++kc) {
      const float4 qv0 = *(const float4*)&qs[wv +  0][k0 + kc * 4];
      const float4 qv1 = *(const float4*)&qs[wv +  4][k0 + kc * 4];
      const float4 qv2 = *(const float4*)&qs[wv +  8][k0 + kc * 4];
      const float4 qv3 = *(const float4*)&qs[wv + 12][k0 + kc * 4];
      FSTEP(0, x) FSTEP(1, y) FSTEP(2, z) FSTEP(3, w)
    }
  }
  __syncthreads();   // wck dead from here; upool becomes s_px/s_py/s_a

  // ---- offsets epilogue (cols 0..255): col e = h*32 + l*8 + p*2 + xy
#pragma unroll
  for (int c = 0; c < 4; ++c) {
    const int col = c * 64 + lane;
    const float bias = off_b[col];
    const int l  = (col >> 3) & 3;
    const int Wl = 128 >> l;
    const float sc = 0.5f * (float)(Wl - 1);
    const int xy = col & 1;
#pragma unroll
    for (int i = 0; i < 4; ++i) {
      const int q = wv + 4 * i;
      float loc = refs[q][l * 2 + xy] + tanhf(acc[c][i] + bias);   // OFFSET_SCALE=1
      loc = fminf(fmaxf(loc, -1.f), 1.f);
      const float pix = (loc + 1.f) * sc;                          // [0, Wl-1]
      const float other = __shfl_xor(pix, 1);                      // partner coordinate
      if ((lane & 1) == 0) {                                       // xy==0 lane holds x
        s_px[q][col >> 1] = pix;                                   // col>>1 = h*16+l*4+p
        s_py[q][col >> 1] = other;
      }
    }
  }

  // ---- attention epilogue (logit index li = h*16 + l*4 + p)
#pragma unroll
  for (int c = 4; c < 6; ++c) {
    const int li = (c - 4) * 64 + lane;
    const float bias = attn_b[li];
#pragma unroll
    for (int i = 0; i < 4; ++i) {
      const int q = wv + 4 * i;
      const float logit = acc[c][i] + bias;
      // softmax over the 16-lane group (one head, fixed q)
      float mx = logit;
#pragma unroll
      for (int msk = 1; msk < 16; msk <<= 1) mx = fmaxf(mx, __shfl_xor(mx, msk));
      const float e = __expf(logit - mx);
      float s = e;
#pragma unroll
      for (int msk = 1; msk < 16; msk <<= 1) s += __shfl_xor(s, msk);
      s_a[q][li] = e / s;
    }
  }

  // ---- sampling: loop over the 16 queries
  for (int q = 0; q < 16; ++q) {
    __syncthreads();
    if (t < 128) {                          // t = h*16 + l*4 + p
      const float a = s_a[q][t];
      const int l  = (t >> 2) & 3;
      const int Wl = 128 >> l;
      const int base = (l == 0) ? 0 : (l == 1) ? 16384 : (l == 2) ? 20480 : 21504;
      const float x = s_px[q][t], y = s_py[q][t];
      const float x0f = floorf(x), y0f = floorf(y);
      const float wx = x - x0f, wy = y - y0f;
      const int x0 = min(max((int)x0f, 0), Wl - 1);
      const int x1 = min(x0 + 1, Wl - 1);
      const int y0 = min(max((int)y0f, 0), Wl - 1);
      const int y1 = min(y0 + 1, Wl - 1);
      s_idx[t * 4 + 0] = base + y0 * Wl + x0;
      s_idx[t * 4 + 1] = base + y0 * Wl + x1;
      s_idx[t * 4 + 2] = base + y1 * Wl + x0;
      s_idx[t * 4 + 3] = base + y1 * Wl + x1;
      s_w[t * 4 + 0] = a * (1.f - wy) * (1.f - wx);
      s_w[t * 4 + 1] = a * (1.f - wy) * wx;
      s_w[t * 4 + 2] = a * wy * (1.f - wx);
      s_w[t * 4 + 3] = a * wy * wx;
    }
    __syncthreads();
    // gather: thread = (h, c); v layout: pix*256 + h*32 + c
    const int h = t >> 5, c = t & 31;
    const float* vb = v_ws + h * 32 + c;
    float acc2 = 0.f;
#pragma unroll
    for (int j = 0; j < 16; ++j) {
      const int g = h * 16 + j;
      acc2 += s_w[g * 4 + 0] * vb[(size_t)s_idx[g * 4 + 0] * 256]
            + s_w[g * 4 + 1] * vb[(size_t)s_idx[g * 4 + 1] * 256]
            + s_w[g * 4 + 2] * vb[(size_t)s_idx[g * 4 + 2] * 256]
            + s_w[g * 4 + 3] * vb[(size_t)s_idx[g * 4 + 3] * 256];
    }
    outpre[(size_t)(qbase + q) * 256 + t] = acc2;   // fp32
  }
}

// ---------------- Kernel 3: in-place output projection (fp32, race-free) ----------------
// One block owns 64 rows of D fully: caches 64x256 fp32 in LDS (padded row
// stride 260 -> 2-way banks = free), then computes all 4 column tiles of
// D = pre @ out_W^T with k-major weight chunks and b128 fragment reads.
#define OSTEP(q, COMP) { \
  const float4 w = *(const float4*)&Wk[kc*4+(q)][tx*4]; \
  acc[0][0]+=a0.COMP*w.x; acc[0][1]+=a0.COMP*w.y; acc[0][2]+=a0.COMP*w.z; acc[0][3]+=a0.COMP*w.w; \
  acc[1][0]+=a1.COMP*w.x; acc[1][1]+=a1.COMP*w.y; acc[1][2]+=a1.COMP*w.z; acc[1][3]+=a1.COMP*w.w; \
  acc[2][0]+=a2.COMP*w.x; acc[2][1]+=a2.COMP*w.y; acc[2][2]+=a2.COMP*w.z; acc[2][3]+=a2.COMP*w.w; \
  acc[3][0]+=a3.COMP*w.x; acc[3][1]+=a3.COMP*w.y; acc[3][2]+=a3.COMP*w.z; acc[3][3]+=a3.COMP*w.w; }

__global__ __launch_bounds__(256)
void gemm_out_inplace(float* __restrict__ D,       // d_out (32768,256) fp32
                      const float* __restrict__ Wout)
{
  __shared__ float As[64][260];   // padded: stride 1040 B (16B-aligned, banks +4/row)
  __shared__ float Wk[16][68];    // k-major weight chunk

  const int t  = threadIdx.x;
  const int tx = t & 15, ty = t >> 4;
  const int bm = blockIdx.x;
  const int lr  = t >> 2;
  const int lc4 = (t & 3) * 4;

  // cache this block's 64 rows (16384 floats = 4096 float4)
#pragma unroll
  for (int i = 0; i < 16; ++i) {
    const int e = t + i * 256;               // float4 index 0..4095
    const int r = e >> 6, cc = e & 63;
    *(float4*)&As[r][cc * 4] = *(const float4*)(D + (size_t)(bm * 64 + r) * 256 + cc * 4);
  }

  for (int bn = 0; bn < 4; ++bn) {
    float acc[4][4] = {};
    for (int k0 = 0; k0 < K_; k0 += 16) {
      __syncthreads();   // protect Wk (and As on first iter) before rewrite
      {
        const float4 vw = *(const float4*)(Wout + (size_t)(bn * 64 + lr) * K_ + k0 + lc4);
        Wk[lc4+0][lr] = vw.x; Wk[lc4+1][lr] = vw.y; Wk[lc4+2][lr] = vw.z; Wk[lc4+3][lr] = vw.w;
      }
      __syncthreads();
#pragma unroll
      for (int kc = 0; kc < 4; ++kc) {
        const float4 a0 = *(const float4*)&As[ty * 4 + 0][k0 + kc * 4];
        const float4 a1 = *(const float4*)&As[ty * 4 + 1][k0 + kc * 4];
        const float4 a2 = *(const float4*)&As[ty * 4 + 2][k0 + kc * 4];
        const float4 a3 = *(const float4*)&As[ty * 4 + 3][k0 + kc * 4];
        OSTEP(0, x) OSTEP(1, y) OSTEP(2, z) OSTEP(3, w)
      }
    }
#pragma unroll
    for (int i = 0; i < 4; ++i)
#pragma unroll
      for (int j = 0; j < 4; ++j) {
        const int gm = bm * 64 + ty * 4 + i;
        const int gn = bn * 64 + tx * 4 + j;
        D[(size_t)gm * 256 + gn] = acc[i][j];    // own rows; As is a private copy
      }
  }
}

extern "C" void kernel_launch(void* const* d_in, const int* in_sizes, int n_in,
                              void* d_out, int out_size, void* d_ws, size_t ws_size,
                              hipStream_t stream)
{
  (void)in_sizes; (void)n_in; (void)out_size; (void)ws_size;
  const float* queries    = (const float*)d_in[0];
  const float* ref_points = (const float*)d_in[1];
  const float* value      = (const float*)d_in[2];
  // d_in[3] = value_spatial_shapes (int32) — compile-time constants here
  const float* V_W    = (const float*)d_in[4];
  const float* off_W  = (const float*)d_in[5];
  const float* off_b  = (const float*)d_in[6];
  const float* attn_W = (const float*)d_in[7];
  const float* attn_b = (const float*)d_in[8];
  const float* out_W  = (const float*)d_in[9];

  // Workspace: one batch of projected values, (21760 x 256) fp32 = 22,282,240 B.
  float* v_ws = (float*)d_ws;

  // Per-batch: vproj(b) -> sample(b); stream order serializes the v_ws reuse.
  for (int b = 0; b < B_; ++b) {
    gemm_vproj<<<dim3(VLEN_ / 64, 4), 256, 0, stream>>>(
        value + (size_t)b * VLEN_ * K_, V_W, v_ws);
    fused_offattn_sample<<<Q_ / 16, 256, 0, stream>>>(
        queries + (size_t)b * Q_ * 256, ref_points + (size_t)b * Q_ * 8,
        off_W, off_b, attn_W, attn_b, v_ws,
        (float*)d_out + (size_t)b * Q_ * 256);
  }
  // Output projection, in place on d_out (race-free).
  gemm_out_inplace<<<(B_ * Q_) / 64, 256, 0, stream>>>((float*)d_out, out_W);
}

// Round 2
// 671.843 us; speedup vs baseline: 1.4224x; 1.1789x over previous
//
#include <hip/hip_runtime.h>
#include <cstdint>
#include <cstddef>

// Problem constants (hardcoded per reference setup_inputs)
#define B_    4
#define Q_    8192
#define E_    256
#define H_    8
#define L_    4
#define P_    4
#define HD_   32
#define VLEN_ 21760   // 128^2 + 64^2 + 32^2 + 16^2
#define K_    256
#define MBLK_ (VLEN_ / 64)   // 340 row-tiles per batch in vproj
#define QBLK_ (Q_ / 16)      // 512 query-tiles per batch in fused

// ---------------- Kernel 1: value projection (fp32), optionally all batches ----------------
// C[pix][n] = sum_k value_b[pix][k] * V_W[n][k]; C row-major (21760, 256) fp32.
// k-major LDS staging so fragment reads are ds_read_b128 (4 k at a time).
#define VSTEP(q) { \
  const float4 av  = *(const float4*)&Ak[kc*4+(q)][ty*4]; \
  const float4 wv4 = *(const float4*)&Wk[kc*4+(q)][tx*4]; \
  acc[0][0]+=av.x*wv4.x; acc[0][1]+=av.x*wv4.y; acc[0][2]+=av.x*wv4.z; acc[0][3]+=av.x*wv4.w; \
  acc[1][0]+=av.y*wv4.x; acc[1][1]+=av.y*wv4.y; acc[1][2]+=av.y*wv4.z; acc[1][3]+=av.y*wv4.w; \
  acc[2][0]+=av.z*wv4.x; acc[2][1]+=av.z*wv4.y; acc[2][2]+=av.z*wv4.z; acc[2][3]+=av.z*wv4.w; \
  acc[3][0]+=av.w*wv4.x; acc[3][1]+=av.w*wv4.y; acc[3][2]+=av.w*wv4.z; acc[3][3]+=av.w*wv4.w; }

__global__ __launch_bounds__(256)
void gemm_vproj(const float* __restrict__ A,      // value (maybe batch 0 base)
                const float* __restrict__ W,      // V_W (256,256)
                float* __restrict__ C,            // v_ws
                size_t a_bstride, size_t c_bstride)
{
  // k-major chunk tiles: [kk][row], row-stride 68 floats (272 B, 16B-aligned, 2-way banks)
  __shared__ float Ak[16][68];
  __shared__ float Wk[16][68];

  const int t  = threadIdx.x;
  const int tx = t & 15, ty = t >> 4;
  const int b  = blockIdx.x / MBLK_;        // batch (0 when grid is per-batch)
  const int bm = blockIdx.x - b * MBLK_;
  const int bn = blockIdx.y;
  const int lr  = t >> 2;          // 0..63: row within tile
  const int lc4 = (t & 3) * 4;     // k offset within chunk

  A += (size_t)b * a_bstride;
  C += (size_t)b * c_bstride;

  float acc[4][4] = {};

  for (int k0 = 0; k0 < K_; k0 += 16) {
    __syncthreads();
    {
      const float4 va = *(const float4*)(A + (size_t)(bm * 64 + lr) * K_ + k0 + lc4);
      Ak[lc4+0][lr] = va.x; Ak[lc4+1][lr] = va.y; Ak[lc4+2][lr] = va.z; Ak[lc4+3][lr] = va.w;
      const float4 vw = *(const float4*)(W + (size_t)(bn * 64 + lr) * K_ + k0 + lc4);
      Wk[lc4+0][lr] = vw.x; Wk[lc4+1][lr] = vw.y; Wk[lc4+2][lr] = vw.z; Wk[lc4+3][lr] = vw.w;
    }
    __syncthreads();
#pragma unroll
    for (int kc = 0; kc < 4; ++kc) {
      VSTEP(0) VSTEP(1) VSTEP(2) VSTEP(3)
    }
  }

#pragma unroll
  for (int i = 0; i < 4; ++i)
#pragma unroll
    for (int j = 0; j < 4; ++j) {
      const int gm = bm * 64 + ty * 4 + i;
      const int gn = bn * 64 + tx * 4 + j;
      C[(size_t)gm * 256 + gn] = acc[i][j];
    }
}

// ---------------- Kernel 2: fused offsets/attn GEMM + softmax + sampling ----------------
// One block = 16 consecutive queries of one batch. Single K-loop GEMM (each
// thread owns 6 output columns), then tap compute for 2 queries per barrier
// (all 256 threads), then float4-vectorized gather with a j2 shuffle-reduce.
#define FSTEP(q, COMP) { \
  const float* wr = &wck[kc*4+(q)][lane]; \
  const float w0=wr[0], w1=wr[64], w2=wr[128], w3=wr[192], w4=wr[256], w5=wr[320]; \
  acc[0][0]+=w0*qv0.COMP; acc[0][1]+=w0*qv1.COMP; acc[0][2]+=w0*qv2.COMP; acc[0][3]+=w0*qv3.COMP; \
  acc[1][0]+=w1*qv0.COMP; acc[1][1]+=w1*qv1.COMP; acc[1][2]+=w1*qv2.COMP; acc[1][3]+=w1*qv3.COMP; \
  acc[2][0]+=w2*qv0.COMP; acc[2][1]+=w2*qv1.COMP; acc[2][2]+=w2*qv2.COMP; acc[2][3]+=w2*qv3.COMP; \
  acc[3][0]+=w3*qv0.COMP; acc[3][1]+=w3*qv1.COMP; acc[3][2]+=w3*qv2.COMP; acc[3][3]+=w3*qv3.COMP; \
  acc[4][0]+=w4*qv0.COMP; acc[4][1]+=w4*qv1.COMP; acc[4][2]+=w4*qv2.COMP; acc[4][3]+=w4*qv3.COMP; \
  acc[5][0]+=w5*qv0.COMP; acc[5][1]+=w5*qv1.COMP; acc[5][2]+=w5*qv2.COMP; acc[5][3]+=w5*qv3.COMP; }

__global__ __launch_bounds__(256)
void fused_offattn_sample(const float* __restrict__ queries,
                          const float* __restrict__ ref_points,
                          const float* __restrict__ off_W,
                          const float* __restrict__ off_b,
                          const float* __restrict__ attn_W,
                          const float* __restrict__ attn_b,
                          const float* __restrict__ v_ws,
                          float* __restrict__ outpre,
                          size_t q_bstride, size_t r_bstride,
                          size_t v_bstride, size_t o_bstride)
{
  __shared__ float qs[16][260];            // query tile fp32 (pad 4, rows 16B-aligned)
  __shared__ float upool[16 * 384];        // union: wck[16][384] | {s_px,s_py,s_a}[16][128]
  __shared__ float refs[16][8];            // ref_points per query (l, xy)
  __shared__ int4   s_idx4[2][128];        // 4 bilinear pixel indices per tap, 2 queries
  __shared__ float4 s_w4[2][128];          // 4 combined weights (attn*bilinear) per tap

  float (*wck)[384]  = (float (*)[384])upool;
  float (*s_px)[128] = (float (*)[128])upool;              // floats [0, 2048)
  float (*s_py)[128] = (float (*)[128])(upool + 16 * 128); // [2048, 4096)
  float (*s_a)[128]  = (float (*)[128])(upool + 32 * 128); // [4096, 6144)

  const int t     = threadIdx.x;
  const int lane  = t & 63;                // column within 64-col group
  const int wv    = t >> 6;                // wave id: q rows {wv, wv+4, wv+8, wv+12}
  const int b     = blockIdx.x >> 9;       // batch (0 when grid is per-batch)
  const int qbase = (blockIdx.x & (QBLK_ - 1)) * 16;

  queries    += (size_t)b * q_bstride;
  ref_points += (size_t)b * r_bstride;
  outpre     += (size_t)b * o_bstride;
  const float4* vws4 = (const float4*)(v_ws + (size_t)b * v_bstride);

  // ---- load query tile + ref points
  {
    const int r  = t >> 4;
    const int c0 = (t & 15) * 16;
    const float4* src = (const float4*)(queries + (size_t)(qbase + r) * K_ + c0);
    *(float4*)&qs[r][c0 + 0]  = src[0];
    *(float4*)&qs[r][c0 + 4]  = src[1];
    *(float4*)&qs[r][c0 + 8]  = src[2];
    *(float4*)&qs[r][c0 + 12] = src[3];
  }
  if (t < 128) refs[t >> 3][t & 7] = ref_points[(size_t)(qbase + (t >> 3)) * 8 + (t & 7)];

  // ---- precompute weight-staging sources: 1536 float4 per chunk, 6 per thread
  const float* wsrc[6]; int wcol[6]; int wm4[6];
#pragma unroll
  for (int n = 0; n < 6; ++n) {
    const int e   = n * 256 + t;           // 0..1535
    const int col = e % 384;               // output column
    const int m   = e / 384;               // k-subgroup (0..3)
    wcol[n] = col; wm4[n] = m * 4;
    wsrc[n] = (col < 256 ? off_W + (size_t)col * K_
                         : attn_W + (size_t)(col - 256) * K_) + m * 4;
  }

  float acc[6][4] = {};   // [col-group c][q-row i]; col = c*64 + lane

  for (int k0 = 0; k0 < K_; k0 += 16) {
    __syncthreads();
#pragma unroll
    for (int n = 0; n < 6; ++n) {
      const float4 v = *(const float4*)(wsrc[n] + k0);
      wck[wm4[n] + 0][wcol[n]] = v.x;
      wck[wm4[n] + 1][wcol[n]] = v.y;
      wck[wm4[n] + 2][wcol[n]] = v.z;
      wck[wm4[n] + 3][wcol[n]] = v.w;
    }
    __syncthreads();
#pragma unroll
    for (int kc = 0; kc < 4; ++kc) {
      const float4 qv0 = *(const float4*)&qs[wv +  0][k0 + kc * 4];
      const float4 qv1 = *(const float4*)&qs[wv +  4][k0 + kc * 4];
      const float4 qv2 = *(const float4*)&qs[wv +  8][k0 + kc * 4];
      const float4 qv3 = *(const float4*)&qs[wv + 12][k0 + kc * 4];
      FSTEP(0, x) FSTEP(1, y) FSTEP(2, z) FSTEP(3, w)
    }
  }
  __syncthreads();   // wck dead from here; upool becomes s_px/s_py/s_a

  // ---- offsets epilogue (cols 0..255): col e = h*32 + l*8 + p*2 + xy
#pragma unroll
  for (int c = 0; c < 4; ++c) {
    const int col = c * 64 + lane;
    const float bias = off_b[col];
    const int l  = (col >> 3) & 3;
    const int Wl = 128 >> l;
    const float sc = 0.5f * (float)(Wl - 1);
    const int xy = col & 1;
#pragma unroll
    for (int i = 0; i < 4; ++i) {
      const int q = wv + 4 * i;
      float loc = refs[q][l * 2 + xy] + tanhf(acc[c][i] + bias);   // OFFSET_SCALE=1
      loc = fminf(fmaxf(loc, -1.f), 1.f);
      const float pix = (loc + 1.f) * sc;                          // [0, Wl-1]
      const float other = __shfl_xor(pix, 1);                      // partner coordinate
      if ((lane & 1) == 0) {                                       // xy==0 lane holds x
        s_px[q][col >> 1] = pix;                                   // col>>1 = h*16+l*4+p
        s_py[q][col >> 1] = other;
      }
    }
  }

  // ---- attention epilogue (logit index li = h*16 + l*4 + p)
#pragma unroll
  for (int c = 4; c < 6; ++c) {
    const int li = (c - 4) * 64 + lane;
    const float bias = attn_b[li];
#pragma unroll
    for (int i = 0; i < 4; ++i) {
      const int q = wv + 4 * i;
      const float logit = acc[c][i] + bias;
      // softmax over the 16-lane group (one head, fixed q)
      float mx = logit;
#pragma unroll
      for (int msk = 1; msk < 16; msk <<= 1) mx = fmaxf(mx, __shfl_xor(mx, msk));
      const float e = __expf(logit - mx);
      float s = e;
#pragma unroll
      for (int msk = 1; msk < 16; msk <<= 1) s += __shfl_xor(s, msk);
      s_a[q][li] = e / s;
    }
  }

  // ---- sampling: 8 query-pairs; tap compute uses all 256 threads
  const int h  = t >> 5;          // head
  const int j2 = (t >> 3) & 3;    // tap-slot split (reduced via shuffles)
  const int c4 = t & 7;           // float4 channel group
  const float4* vb = vws4 + h * 8 + c4;   // row stride = 64 float4 (256 floats)

  for (int qp = 0; qp < 8; ++qp) {
    __syncthreads();              // s_idx4/s_w4 free; also orders epilogue writes (qp=0)
    {
      const int u  = t >> 7;      // which query of the pair
      const int g  = t & 127;     // tap index h*16 + l*4 + p
      const int qq = qp * 2 + u;
      const float a = s_a[qq][g];
      const int l  = (g >> 2) & 3;
      const int Wl = 128 >> l;
      const int base = (l == 0) ? 0 : (l == 1) ? 16384 : (l == 2) ? 20480 : 21504;
      const float x = s_px[qq][g], y = s_py[qq][g];
      const float x0f = floorf(x), y0f = floorf(y);
      const float wx = x - x0f, wy = y - y0f;
      const int x0 = min(max((int)x0f, 0), Wl - 1);
      const int x1 = min(x0 + 1, Wl - 1);
      const int y0 = min(max((int)y0f, 0), Wl - 1);
      const int y1 = min(y0 + 1, Wl - 1);
      s_idx4[u][g] = make_int4(base + y0 * Wl + x0, base + y0 * Wl + x1,
                               base + y1 * Wl + x0, base + y1 * Wl + x1);
      s_w4[u][g] = make_float4(a * (1.f - wy) * (1.f - wx), a * (1.f - wy) * wx,
                               a * wy * (1.f - wx),          a * wy * wx);
    }
    __syncthreads();
#pragma unroll
    for (int u = 0; u < 2; ++u) {
      float4 o = {0.f, 0.f, 0.f, 0.f};
#pragma unroll
      for (int jj = 0; jj < 4; ++jj) {
        const int g = h * 16 + jj * 4 + j2;
        const int4   id = s_idx4[u][g];
        const float4 w  = s_w4[u][g];
        const float4 v0 = vb[(size_t)id.x * 64];
        const float4 v1 = vb[(size_t)id.y * 64];
        const float4 v2 = vb[(size_t)id.z * 64];
        const float4 v3 = vb[(size_t)id.w * 64];
        o.x += w.x * v0.x + w.y * v1.x + w.z * v2.x + w.w * v3.x;
        o.y += w.x * v0.y + w.y * v1.y + w.z * v2.y + w.w * v3.y;
        o.z += w.x * v0.z + w.y * v1.z + w.z * v2.z + w.w * v3.z;
        o.w += w.x * v0.w + w.y * v1.w + w.z * v2.w + w.w * v3.w;
      }
      // reduce over j2 (lanes ^8, ^16 share h and c4)
      o.x += __shfl_xor(o.x, 8);  o.y += __shfl_xor(o.y, 8);
      o.z += __shfl_xor(o.z, 8);  o.w += __shfl_xor(o.w, 8);
      o.x += __shfl_xor(o.x, 16); o.y += __shfl_xor(o.y, 16);
      o.z += __shfl_xor(o.z, 16); o.w += __shfl_xor(o.w, 16);
      if (j2 == 0)
        *(float4*)(outpre + (size_t)(qbase + qp * 2 + u) * 256 + h * 32 + c4 * 4) = o;
    }
  }
}

// ---------------- Kernel 3: in-place output projection (fp32, race-free) ----------------
#define OSTEP(q, COMP) { \
  const float4 w = *(const float4*)&Wk[kc*4+(q)][tx*4]; \
  acc[0][0]+=a0.COMP*w.x; acc[0][1]+=a0.COMP*w.y; acc[0][2]+=a0.COMP*w.z; acc[0][3]+=a0.COMP*w.w; \
  acc[1][0]+=a1.COMP*w.x; acc[1][1]+=a1.COMP*w.y; acc[1][2]+=a1.COMP*w.z; acc[1][3]+=a1.COMP*w.w; \
  acc[2][0]+=a2.COMP*w.x; acc[2][1]+=a2.COMP*w.y; acc[2][2]+=a2.COMP*w.z; acc[2][3]+=a2.COMP*w.w; \
  acc[3][0]+=a3.COMP*w.x; acc[3][1]+=a3.COMP*w.y; acc[3][2]+=a3.COMP*w.z; acc[3][3]+=a3.COMP*w.w; }

__global__ __launch_bounds__(256)
void gemm_out_inplace(float* __restrict__ D,       // d_out (32768,256) fp32
                      const float* __restrict__ Wout)
{
  __shared__ float As[64][260];   // padded: stride 1040 B (16B-aligned, banks +4/row)
  __shared__ float Wk[16][68];    // k-major weight chunk

  const int t  = threadIdx.x;
  const int tx = t & 15, ty = t >> 4;
  const int bm = blockIdx.x;
  const int lr  = t >> 2;
  const int lc4 = (t & 3) * 4;

  // cache this block's 64 rows (16384 floats = 4096 float4)
#pragma unroll
  for (int i = 0; i < 16; ++i) {
    const int e = t + i * 256;               // float4 index 0..4095
    const int r = e >> 6, cc = e & 63;
    *(float4*)&As[r][cc * 4] = *(const float4*)(D + (size_t)(bm * 64 + r) * 256 + cc * 4);
  }

  for (int bn = 0; bn < 4; ++bn) {
    float acc[4][4] = {};
    for (int k0 = 0; k0 < K_; k0 += 16) {
      __syncthreads();   // protect Wk (and As on first iter) before rewrite
      {
        const float4 vw = *(const float4*)(Wout + (size_t)(bn * 64 + lr) * K_ + k0 + lc4);
        Wk[lc4+0][lr] = vw.x; Wk[lc4+1][lr] = vw.y; Wk[lc4+2][lr] = vw.z; Wk[lc4+3][lr] = vw.w;
      }
      __syncthreads();
#pragma unroll
      for (int kc = 0; kc < 4; ++kc) {
        const float4 a0 = *(const float4*)&As[ty * 4 + 0][k0 + kc * 4];
        const float4 a1 = *(const float4*)&As[ty * 4 + 1][k0 + kc * 4];
        const float4 a2 = *(const float4*)&As[ty * 4 + 2][k0 + kc * 4];
        const float4 a3 = *(const float4*)&As[ty * 4 + 3][k0 + kc * 4];
        OSTEP(0, x) OSTEP(1, y) OSTEP(2, z) OSTEP(3, w)
      }
    }
#pragma unroll
    for (int i = 0; i < 4; ++i)
#pragma unroll
      for (int j = 0; j < 4; ++j) {
        const int gm = bm * 64 + ty * 4 + i;
        const int gn = bn * 64 + tx * 4 + j;
        D[(size_t)gm * 256 + gn] = acc[i][j];    // own rows; As is a private copy
      }
  }
}

extern "C" void kernel_launch(void* const* d_in, const int* in_sizes, int n_in,
                              void* d_out, int out_size, void* d_ws, size_t ws_size,
                              hipStream_t stream)
{
  (void)in_sizes; (void)n_in; (void)out_size;
  const float* queries    = (const float*)d_in[0];
  const float* ref_points = (const float*)d_in[1];
  const float* value      = (const float*)d_in[2];
  // d_in[3] = value_spatial_shapes (int32) — compile-time constants here
  const float* V_W    = (const float*)d_in[4];
  const float* off_W  = (const float*)d_in[5];
  const float* off_b  = (const float*)d_in[6];
  const float* attn_W = (const float*)d_in[7];
  const float* attn_b = (const float*)d_in[8];
  const float* out_W  = (const float*)d_in[9];

  float* v_ws = (float*)d_ws;
  const size_t vb_elems = (size_t)VLEN_ * K_;            // floats per batch of v_ws

  if (ws_size >= (size_t)B_ * vb_elems * sizeof(float)) {
    // Batched path: one vproj launch (all batches), one fused launch (all batches).
    gemm_vproj<<<dim3(B_ * MBLK_, 4), 256, 0, stream>>>(
        value, V_W, v_ws, vb_elems, vb_elems);
    fused_offattn_sample<<<B_ * QBLK_, 256, 0, stream>>>(
        queries, ref_points, off_W, off_b, attn_W, attn_b, v_ws, (float*)d_out,
        (size_t)Q_ * K_, (size_t)Q_ * 8, vb_elems, (size_t)Q_ * 256);
  } else {
    // Fallback: workspace holds one batch only; serialize per batch.
    for (int b = 0; b < B_; ++b) {
      gemm_vproj<<<dim3(MBLK_, 4), 256, 0, stream>>>(
          value + (size_t)b * VLEN_ * K_, V_W, v_ws, 0, 0);
      fused_offattn_sample<<<QBLK_, 256, 0, stream>>>(
          queries + (size_t)b * Q_ * K_, ref_points + (size_t)b * Q_ * 8,
          off_W, off_b, attn_W, attn_b, v_ws,
          (float*)d_out + (size_t)b * Q_ * 256, 0, 0, 0, 0);
    }
  }
  // Output projection, in place on d_out (race-free).
  gemm_out_inplace<<<(B_ * Q_) / 64, 256, 0, stream>>>((float*)d_out, out_W);
}